// Round 11
// baseline (435.721 us; speedup 1.0000x reference)
//
#include <hip/hip_runtime.h>

typedef __bf16 bf16x8 __attribute__((ext_vector_type(8)));
typedef float  f32x4  __attribute__((ext_vector_type(4)));

constexpr int Bn = 16, Cn = 256, Hn = 64, Wn = 64, HWn = 64 * 64;
constexpr int Ntot = Bn * HWn;  // 65536 pixels

#define DEV static __device__ __forceinline__

DEV unsigned short f2bf(float f) {
  unsigned u = __builtin_bit_cast(unsigned, f);
  u += 0x7fffu + ((u >> 16) & 1u);   // RNE
  return (unsigned short)(u >> 16);
}
DEV float bf2f(unsigned short s) {
  unsigned u = ((unsigned)s) << 16;
  return __builtin_bit_cast(float, u);
}
DEV bf16x8 asbf(uint4 u) { return __builtin_bit_cast(bf16x8, u); }

// ---------------- K0: weights -> bf16 ----------------
// Aqv: [t][o512][c256];  Aoff: [t][o16][tap9][c256];
// Aout PACKED fragment-order: Apk[seg64][o256][e8], seg = k/8 (k over 512)
__global__ void k_prep(const float* qw, const float* kvrw, const float* kvtw,
                       const float* offrw, const float* offtw, const float* outw,
                       unsigned short* Aqv, unsigned short* Aoff, unsigned short* Aout) {
  int idx = blockIdx.x * 256 + threadIdx.x;
  if (idx < 2 * 512 * 256) {
    int t = idx >> 17; int r = idx & 131071; int o = r >> 8; int c = r & 255;
    float v = (o < 256) ? qw[o * 256 + c] : (t ? kvtw[o * 256 + c] : kvrw[o * 256 + c]);
    Aqv[idx] = f2bf(v);
    return;
  }
  idx -= 2 * 512 * 256;
  if (idx < 2 * 16 * 2304) {
    int t = idx / 36864; int r = idx % 36864;
    int o = r / 2304; int rc = r % 2304; int tap = rc >> 8; int c = rc & 255;
    const float* w = t ? offtw : offrw;
    float v = (o < 8) ? w[(o * 256 + c) * 9 + tap] : 0.f;
    Aoff[idx] = f2bf(v);
    return;
  }
  idx -= 2 * 16 * 2304;
  if (idx < 256 * 512) {
    int seg = idx >> 11, o = (idx >> 3) & 255, e = idx & 7;
    Aout[idx] = f2bf(outw[o * 512 + seg * 8 + e]);
  }
}

// ---------------- K1: NCHW f32 -> NHWC bf16 transpose ----------------
__global__ void k_transpose(const float* rgb, const float* th, unsigned short* xT) {
  int bi = blockIdx.x;
  int ct = bi & 3;
  int nt = (bi >> 2) & 63;
  int b  = (bi >> 8) & 15;
  int t  = bi >> 12;
  const float* src = t ? th : rgb;
  int c0 = ct * 64, n0 = nt * 64;
  __shared__ float tile[64][65];
  int tid = threadIdx.x;
  int nl = tid & 63, cg = tid >> 6;
#pragma unroll
  for (int i = 0; i < 16; i++) {
    int c = cg * 16 + i;
    tile[c][nl] = src[(size_t)(b * 256 + c0 + c) * HWn + n0 + nl];
  }
  __syncthreads();
  int pr = tid >> 2, sg = tid & 3;
  unsigned short tmp[16];
#pragma unroll
  for (int j = 0; j < 16; j++) tmp[j] = f2bf(tile[sg * 16 + j][pr]);
  unsigned short* dst = xT + (size_t)t * Ntot * 256 +
                        (size_t)(b * HWn + n0 + pr) * 256 + c0 + sg * 16;
  *(uint4*)(dst)     = *(const uint4*)(tmp);
  *(uint4*)(dst + 8) = *(const uint4*)(tmp + 8);
}

// ---------------- K2: QV GEMM (BM=128,BN=128,BK=64; coalesced epilogue) ----
__global__ __launch_bounds__(512, 2) void k_qv(
    const unsigned short* Aqv, const unsigned short* xT,
    const float* qb, const float* kvrb, const float* kvtb,
    unsigned short* qs, unsigned short* vv) {
  __shared__ unsigned short smem[32768];   // 64 KB: K-loop dbuf; reused by epilogue
  int t  = blockIdx.z;
  int mt = blockIdx.y;
  int nt = blockIdx.x;
  int swznt = ((nt & 7) << 6) | (nt >> 3);   // XCD-chunked, bijective (512 % 8 == 0)
  int o0 = mt * 128;
  int n0 = swznt * 128;
  int tid = threadIdx.x;
  const unsigned short* Aq = Aqv + t * 512 * 256;
  const unsigned short* Xg = xT + (size_t)t * Ntot * 256 + (size_t)n0 * 256;

  auto stage = [&](int kb, int bb) {
    unsigned short* As = smem + bb * 8192;
    unsigned short* Xs = smem + 16384 + bb * 8192;
#pragma unroll
    for (int i = 0; i < 2; i++) {
      int cid = tid + i * 512;
      int row = cid >> 3, seg = cid & 7;
      int ss = seg ^ (row & 7);
      *(uint4*)(&As[row * 64 + seg * 8]) =
          *(const uint4*)(Aq + (size_t)(o0 + row) * 256 + kb * 64 + ss * 8);
    }
#pragma unroll
    for (int i = 0; i < 2; i++) {
      int cid = tid + i * 512;
      int row = cid >> 3, seg = cid & 7;
      int ss = seg ^ (row & 7);
      *(uint4*)(&Xs[row * 64 + seg * 8]) =
          *(const uint4*)(Xg + (size_t)row * 256 + kb * 64 + ss * 8);
    }
  };

  int w = __builtin_amdgcn_readfirstlane(tid >> 6);
  int lane = tid & 63;
  int wo = w & 1, wn = w >> 1;   // 2x64 o-rows, 4x32 pixels
  int r16 = lane & 15, q4 = lane >> 4;

  f32x4 acc[4][2];
#pragma unroll
  for (int a = 0; a < 4; a++) { acc[a][0] = f32x4{0.f,0.f,0.f,0.f}; acc[a][1] = f32x4{0.f,0.f,0.f,0.f}; }

  stage(0, 0);
  __syncthreads();
#pragma unroll
  for (int kb = 0; kb < 4; kb++) {
    if (kb < 3) stage(kb + 1, (kb + 1) & 1);
    const unsigned short* As = smem + (kb & 1) * 8192;
    const unsigned short* Xs = smem + 16384 + (kb & 1) * 8192;
#pragma unroll
    for (int ks = 0; ks < 2; ks++) {
      uint4 af[4], bfr[2];
#pragma unroll
      for (int oi = 0; oi < 4; oi++) {
        int row = wo * 64 + oi * 16 + r16;
        int seg = (ks * 4 + q4) ^ (row & 7);
        af[oi] = *(const uint4*)(&As[row * 64 + seg * 8]);
      }
#pragma unroll
      for (int ni = 0; ni < 2; ni++) {
        int row = wn * 32 + ni * 16 + r16;
        int seg = (ks * 4 + q4) ^ (row & 7);
        bfr[ni] = *(const uint4*)(&Xs[row * 64 + seg * 8]);
      }
#pragma unroll
      for (int oi = 0; oi < 4; oi++)
#pragma unroll
        for (int ni = 0; ni < 2; ni++)
          acc[oi][ni] = __builtin_amdgcn_mfma_f32_16x16x32_bf16(
              asbf(af[oi]), asbf(bfr[ni]), acc[oi][ni], 0, 0, 0);
    }
    __syncthreads();
  }

  // epilogue: bias (+sigmoid for q) -> LDS [128 n][132 o-pad] -> coalesced global
  bool isq = (mt < 2);
  const float* bias = isq ? qb : (t ? kvtb : kvrb);
  float4 bv[4];
#pragma unroll
  for (int oi = 0; oi < 4; oi++)
    bv[oi] = *(const float4*)(&bias[o0 + wo * 64 + oi * 16 + q4 * 4]);
#pragma unroll
  for (int oi = 0; oi < 4; oi++) {
    int ol = wo * 64 + oi * 16 + q4 * 4;
#pragma unroll
    for (int ni = 0; ni < 2; ni++) {
      int nl = wn * 32 + ni * 16 + r16;
      unsigned short pk[4];
#pragma unroll
      for (int j = 0; j < 4; j++) {
        float val = acc[oi][ni][j] + ((const float*)&bv[oi])[j];
        if (isq) val = 1.f / (1.f + __expf(-val));
        pk[j] = f2bf(val);
      }
      *(uint2*)(&smem[nl * 132 + ol]) = *(const uint2*)(pk);
    }
  }
  __syncthreads();
  unsigned short* outp = (isq ? qs : vv) + (size_t)t * Ntot * 256 + (mt & 1) * 128;
#pragma unroll
  for (int pass = 0; pass < 4; pass++) {
    int nl = pass * 32 + (tid >> 4);
    int c  = tid & 15;
    uint4 vq = *(const uint4*)(&smem[nl * 132 + c * 8]);
    *(uint4*)(outp + (size_t)(n0 + nl) * 256 + c * 8) = vq;
  }
}

// ---------------- K3: 3x3 offset conv. LDS weights, pipelined B loads ----------------
__global__ __launch_bounds__(256, 4) void k_off(
    const unsigned short* Aoff, const unsigned short* xT,
    const float* offrb, const float* offtb, float* offo) {
  __shared__ unsigned short Alds[9 * 8 * 264 + 264];  // 38544 B
  int t  = blockIdx.y;
  int bh = blockIdx.x;
  int swz = ((bh & 7) << 7) | (bh >> 3);   // XCD-chunked, bijective
  int b = swz >> 6, h = swz & 63;
  int tid = threadIdx.x;
  const unsigned short* Aw = Aoff + t * 36864;   // [row16][tap9][c256]

#pragma unroll
  for (int i = 0; i < 9; i++) {
    int cid = tid + i * 256;
    int o = cid / 288;
    int rem = cid - o * 288;
    int tap = rem >> 5, cg = rem & 31;
    uint4 v = *(const uint4*)(Aw + o * 2304 + tap * 256 + cg * 8);
    *(uint4*)(&Alds[(tap * 8 + o) * 264 + cg * 8]) = v;
  }
  if (tid < 33) {
    uint4 z; z.x = 0; z.y = 0; z.z = 0; z.w = 0;
    *(uint4*)(&Alds[19008 + tid * 8]) = z;
  }
  __syncthreads();

  int lane = tid & 63, w = tid >> 6;
  int r16 = lane & 15, q4 = lane >> 4;
  int wl = w * 16 + r16;
  const unsigned short* xin = xT + (size_t)(t ? 0 : 1) * Ntot * 256;
  int zbase = 19008 + q4 * 8;
  int abase = r16 * 264 + q4 * 8;
  bool rowok = (r16 < 8);

  f32x4 acc = {0.f, 0.f, 0.f, 0.f};
  uint4 bufA[8], bufB[8];

#define LOADT(buf, tap) {                                                      \
    int dy = (tap) / 3 - 1, dx = (tap) % 3 - 1;                                \
    int hh = h + dy, ww = wl + dx;                                             \
    bool ok = (hh >= 0 && hh < 64 && ww >= 0 && ww < 64);                      \
    int hc = hh < 0 ? 0 : (hh > 63 ? 63 : hh);                                 \
    int wc = ww < 0 ? 0 : (ww > 63 ? 63 : ww);                                 \
    const unsigned short* p =                                                  \
        xin + (size_t)(((b * 64 + hc) * 64 + wc) * 256) + q4 * 8;              \
    _Pragma("unroll") for (int ks = 0; ks < 8; ks++) {                         \
      uint4 v = *(const uint4*)(p + ks * 32);                                  \
      if (!ok) { v.x = 0; v.y = 0; v.z = 0; v.w = 0; }                         \
      buf[ks] = v;                                                             \
    } }

#define COMPT(buf, tap) {                                                      \
    _Pragma("unroll") for (int ks = 0; ks < 8; ks++) {                         \
      int aofs = rowok ? ((tap) * 8 * 264 + abase + ks * 32) : (zbase + ks * 32); \
      uint4 af = *(const uint4*)(&Alds[aofs]);                                 \
      acc = __builtin_amdgcn_mfma_f32_16x16x32_bf16(asbf(af), asbf(buf[ks]),   \
                                                    acc, 0, 0, 0);             \
    } }

  LOADT(bufA, 0)
  LOADT(bufB, 1)
  COMPT(bufA, 0)
  LOADT(bufA, 2)
  COMPT(bufB, 1)
  LOADT(bufB, 3)
  COMPT(bufA, 2)
  LOADT(bufA, 4)
  COMPT(bufB, 3)
  LOADT(bufB, 5)
  COMPT(bufA, 4)
  LOADT(bufA, 6)
  COMPT(bufB, 5)
  LOADT(bufB, 7)
  COMPT(bufA, 6)
  LOADT(bufA, 8)
  COMPT(bufB, 7)
  COMPT(bufA, 8)
#undef LOADT
#undef COMPT

  if (lane < 32) {
    const float* ob = t ? offtb : offrb;
    int n = (b * 64 + h) * 64 + wl;
    float4 r;
    r.x = acc[0] + ob[q4 * 4 + 0];
    r.y = acc[1] + ob[q4 * 4 + 1];
    r.z = acc[2] + ob[q4 * 4 + 2];
    r.w = acc[3] + ob[q4 * 4 + 3];
    *(float4*)(offo + (size_t)t * Ntot * 8 + (size_t)n * 8 + q4 * 4) = r;
  }
}

// ---------------- K4: fused deform-gather + attn + final GEMM + skip + BN partials --
// v4: identical to v3 but __launch_bounds__(512,3) — compiler already uses 84
// VGPR, cap at 3 blocks/CU is ~85 -> +50% resident waves, no spills.
__global__ __launch_bounds__(512, 3) void k_fuse(
    const unsigned short* qs, const unsigned short* vv, const float* offo,
    const unsigned short* Apk, const float* outb,
    const float* rgb, const float* th, float* dout, float* partial) {
  __shared__ unsigned short cc[32 * 512];    // [pxL][512ch] XOR-swizzled, 32KB
  __shared__ float bstat[256][2];
  int tid = threadIdx.x;
  int bi  = blockIdx.x;                       // 2048
  int swz = ((bi & 7) << 8) | (bi >> 3);      // XCD-chunked, bijective
  int b = swz >> 7, rem = swz & 127;
  int h = rem >> 1, px0 = (rem & 1) * 32;
  if (tid < 256) { bstat[tid][0] = 0.f; bstat[tid][1] = 0.f; }

  // ---- phase 1: gather ----
  {
    int pxL = tid >> 4, chunk = tid & 15;
    int px = px0 + pxL;
    int n = (b * 64 + h) * 64 + px;
    int c0 = chunk * 8;          // ch [c0,+8) and [c0+128,+8) per pass
    int sw = pxL & 7;
#pragma unroll
    for (int pass = 0; pass < 2; pass++) {
      // pass0 -> ch 0..255  = sig(q_rgb) * deform(v_th, off_th2rgb)
      // pass1 -> ch 256..511 = sig(q_th) * deform(v_rgb, off_rgb2th)
      const unsigned short* vsrc = vv + (size_t)(pass ? 0 : 1) * Ntot * 256;
      const float* offp = offo + (size_t)(pass ? 0 : 1) * Ntot * 8 + (size_t)n * 8;
      const unsigned short* qsrc = qs + (size_t)(pass ? 1 : 0) * Ntot * 256 + (size_t)n * 256;
      uint4 q0 = *(const uint4*)(qsrc + c0);
      uint4 q1 = *(const uint4*)(qsrc + c0 + 128);
      float acc[16];
#pragma unroll
      for (int i = 0; i < 16; i++) acc[i] = 0.f;
#pragma unroll
      for (int p = 0; p < 4; p++) {
        float dx = offp[2 * p], dy = offp[2 * p + 1];
        float xf = (float)px + dx * (63.f / 64.f);
        float yf = (float)h  + dy * (63.f / 64.f);
        float x0f = floorf(xf), y0f = floorf(yf);
        float wx = xf - x0f, wy = yf - y0f;
        int x0 = (int)x0f, y0 = (int)y0f;
        float cwgt[4];
        const unsigned short* gp[4];
#pragma unroll
        for (int c = 0; c < 4; c++) {
          int cy2 = c >> 1, cx2 = c & 1;
          int ix = x0 + cx2, iy = y0 + cy2;
          bool ok = (ix >= 0 && ix < 64 && iy >= 0 && iy < 64);
          int ixc = ix < 0 ? 0 : (ix > 63 ? 63 : ix);
          int iyc = iy < 0 ? 0 : (iy > 63 ? 63 : iy);
          float wgt = (cx2 ? wx : 1.f - wx) * (cy2 ? wy : 1.f - wy);
          cwgt[c] = ok ? wgt : 0.f;
          gp[c] = vsrc + (size_t)(((b * 64 + iyc) * 64 + ixc) * 256 + c0);
        }
        // batch all 8 loads, then FMA (keeps 8 loads in flight)
        uint4 r0a = *(const uint4*)(gp[0]);
        uint4 r1a = *(const uint4*)(gp[0] + 128);
        uint4 r0b = *(const uint4*)(gp[1]);
        uint4 r1b = *(const uint4*)(gp[1] + 128);
        uint4 r0c = *(const uint4*)(gp[2]);
        uint4 r1c = *(const uint4*)(gp[2] + 128);
        uint4 r0d = *(const uint4*)(gp[3]);
        uint4 r1d = *(const uint4*)(gp[3] + 128);
#define FMA8(lo, hi, wv)  {                                                    \
        const unsigned short* a0 = (const unsigned short*)&(lo);               \
        const unsigned short* a1 = (const unsigned short*)&(hi);               \
        _Pragma("unroll") for (int e = 0; e < 8; e++) {                        \
          acc[e]     += (wv) * bf2f(a0[e]);                                    \
          acc[8 + e] += (wv) * bf2f(a1[e]);                                    \
        } }
        FMA8(r0a, r1a, cwgt[0])
        FMA8(r0b, r1b, cwgt[1])
        FMA8(r0c, r1c, cwgt[2])
        FMA8(r0d, r1d, cwgt[3])
#undef FMA8
      }
      const unsigned short* qp0 = (const unsigned short*)&q0;
      const unsigned short* qp1 = (const unsigned short*)&q1;
      unsigned short pk[16];
#pragma unroll
      for (int e = 0; e < 8; e++) {
        pk[e]     = f2bf(0.25f * acc[e]     * bf2f(qp0[e]));
        pk[8 + e] = f2bf(0.25f * acc[8 + e] * bf2f(qp1[e]));
      }
      *(uint4*)(&cc[pxL * 512 + ((pass * 32 + chunk)      ^ sw) * 8]) = *(const uint4*)(pk);
      *(uint4*)(&cc[pxL * 512 + ((pass * 32 + 16 + chunk) ^ sw) * 8]) = *(const uint4*)(pk + 8);
    }
  }
  __syncthreads();

  // ---- phase 2: GEMM 256 o x 32 px ----
  int lane = tid & 63, wv = tid >> 6;
  int wo = wv >> 1, wn = wv & 1;   // wo: 4 x 64 o, wn: 2 x 16 px
  int r16 = lane & 15, q4 = lane >> 4;
  f32x4 acc2[4];
#pragma unroll
  for (int a = 0; a < 4; a++) acc2[a] = f32x4{0.f, 0.f, 0.f, 0.f};
#pragma unroll
  for (int kst = 0; kst < 16; kst++) {
    int row = wn * 16 + r16;
    int slot = (kst * 4 + q4) ^ (row & 7);
    uint4 bfr = *(const uint4*)(&cc[row * 512 + slot * 8]);
#pragma unroll
    for (int oi = 0; oi < 4; oi++) {
      int o = wo * 64 + oi * 16 + r16;
      uint4 a = *(const uint4*)(Apk + (size_t)((kst * 4 + q4) * 256 + o) * 8);
      acc2[oi] = __builtin_amdgcn_mfma_f32_16x16x32_bf16(asbf(a), asbf(bfr), acc2[oi], 0, 0, 0);
    }
  }
  // epilogue: bias + skip + store + BN partials
#pragma unroll
  for (int oi = 0; oi < 4; oi++) {
    int ob = wo * 64 + oi * 16 + q4 * 4;
#pragma unroll
    for (int j = 0; j < 4; j++) {
      int o = ob + j;
      int pl = wn * 16 + r16;
      int hw = h * 64 + px0 + pl;
      size_t gidx = (size_t)(b * 256 + o) * HWn + hw;
      float val = acc2[oi][j] + outb[o] + 0.5f * (rgb[gidx] + th[gidx]);
      dout[gidx] = val;
      float s1 = val, s2 = val * val;
#pragma unroll
      for (int m = 1; m < 16; m <<= 1) {
        s1 += __shfl_xor(s1, m, 16);
        s2 += __shfl_xor(s2, m, 16);
      }
      if (r16 == 0) { atomicAdd(&bstat[o][0], s1); atomicAdd(&bstat[o][1], s2); }
    }
  }
  __syncthreads();
  if (tid < 256) {
    partial[(size_t)bi * 512 + tid]       = bstat[tid][0];
    partial[(size_t)bi * 512 + 256 + tid] = bstat[tid][1];
  }
}

// ---------------- K5: reduce partials -> scale/shift ----------------
__global__ void k_stats(const float* partial, const float* gamma, const float* beta,
                        float* sstats) {
  int c = blockIdx.x, tid = threadIdx.x;
  float s1 = 0.f, s2 = 0.f;
  for (int i = tid; i < 2048; i += 256) {
    s1 += partial[(size_t)i * 512 + c];
    s2 += partial[(size_t)i * 512 + 256 + c];
  }
  __shared__ float r1[256], r2[256];
  r1[tid] = s1; r2[tid] = s2;
  __syncthreads();
  for (int st = 128; st > 0; st >>= 1) {
    if (tid < st) { r1[tid] += r1[tid + st]; r2[tid] += r2[tid + st]; }
    __syncthreads();
  }
  if (tid == 0) {
    float mean = r1[0] / 65536.f;
    float var  = r2[0] / 65536.f - mean * mean;
    float scale = gamma[c] / sqrtf(var + 1e-5f);
    sstats[c]       = scale;
    sstats[256 + c] = beta[c] - mean * scale;
  }
}

// ---------------- K6: BN apply in-place on d_out ----------------
__global__ void k_bn(float* dout, const float* sstats) {
  int idx = blockIdx.x * 256 + threadIdx.x;
  size_t base = (size_t)idx * 4;
  int c = (int)((base >> 12) & 255);
  float4 v = *(float4*)(dout + base);
  float sc = sstats[c], sh = sstats[256 + c];
  v.x = v.x * sc + sh; v.y = v.y * sc + sh;
  v.z = v.z * sc + sh; v.w = v.w * sc + sh;
  *(float4*)(dout + base) = v;
}

extern "C" void kernel_launch(void* const* d_in, const int* in_sizes, int n_in,
                              void* d_out, int out_size, void* d_ws, size_t ws_size,
                              hipStream_t stream) {
  const float* rgb   = (const float*)d_in[0];
  const float* th    = (const float*)d_in[1];
  const float* qw    = (const float*)d_in[2];
  const float* qb    = (const float*)d_in[3];
  const float* kvrw  = (const float*)d_in[4];
  const float* kvrb  = (const float*)d_in[5];
  const float* kvtw  = (const float*)d_in[6];
  const float* kvtb  = (const float*)d_in[7];
  const float* offrw = (const float*)d_in[8];
  const float* offrb = (const float*)d_in[9];
  const float* offtw = (const float*)d_in[10];
  const float* offtb = (const float*)d_in[11];
  const float* outw  = (const float*)d_in[12];
  const float* outb  = (const float*)d_in[13];
  const float* gamma = (const float*)d_in[14];
  const float* beta  = (const float*)d_in[15];
  float* dout = (float*)d_out;

  unsigned short* xT   = (unsigned short*)d_ws;       // 64 MB
  unsigned short* qsb  = xT  + (size_t)2 * Ntot * 256;
  unsigned short* vvb  = qsb + (size_t)2 * Ntot * 256;
  float* offo          = (float*)(vvb + (size_t)2 * Ntot * 256);
  unsigned short* Aqv  = (unsigned short*)(offo + (size_t)2 * Ntot * 8);
  unsigned short* Aoff = Aqv + 2 * 512 * 256;
  unsigned short* Aout = Aoff + 2 * 16 * 2304;        // packed Apk
  float* partial       = (float*)(Aout + 256 * 512);  // 2048 * 512 f32
  float* sstats        = partial + (size_t)2048 * 512;

  k_prep<<<1824, 256, 0, stream>>>(qw, kvrw, kvtw, offrw, offtw, outw, Aqv, Aoff, Aout);
  k_transpose<<<8192, 256, 0, stream>>>(rgb, th, xT);
  k_qv<<<dim3(512, 4, 2), 512, 0, stream>>>(Aqv, xT, qb, kvrb, kvtb, qsb, vvb);
  k_off<<<dim3(1024, 2), 256, 0, stream>>>(Aoff, xT, offrb, offtb, offo);
  k_fuse<<<2048, 512, 0, stream>>>(qsb, vvb, offo, Aout, outb, rgb, th, dout, partial);
  k_stats<<<256, 256, 0, stream>>>(partial, gamma, beta, sstats);
  k_bn<<<16384, 256, 0, stream>>>(dout, sstats);
}

// Round 12
// 397.842 us; speedup vs baseline: 1.0952x; 1.0952x over previous
//
#include <hip/hip_runtime.h>

typedef __bf16 bf16x8 __attribute__((ext_vector_type(8)));
typedef float  f32x4  __attribute__((ext_vector_type(4)));

constexpr int Bn = 16, Cn = 256, Hn = 64, Wn = 64, HWn = 64 * 64;
constexpr int Ntot = Bn * HWn;  // 65536 pixels

#define DEV static __device__ __forceinline__

DEV unsigned short f2bf(float f) {
  unsigned u = __builtin_bit_cast(unsigned, f);
  u += 0x7fffu + ((u >> 16) & 1u);   // RNE
  return (unsigned short)(u >> 16);
}
DEV float bf2f(unsigned short s) {
  unsigned u = ((unsigned)s) << 16;
  return __builtin_bit_cast(float, u);
}
DEV bf16x8 asbf(uint4 u) { return __builtin_bit_cast(bf16x8, u); }

// ---------------- K0: weights -> bf16 ----------------
// Aqv: [t][o512][c256];  Aoff: [t][o16][tap9][c256];
// Aout PACKED fragment-order: Apk[seg64][o256][e8], seg = k/8 (k over 512)
__global__ void k_prep(const float* qw, const float* kvrw, const float* kvtw,
                       const float* offrw, const float* offtw, const float* outw,
                       unsigned short* Aqv, unsigned short* Aoff, unsigned short* Aout) {
  int idx = blockIdx.x * 256 + threadIdx.x;
  if (idx < 2 * 512 * 256) {
    int t = idx >> 17; int r = idx & 131071; int o = r >> 8; int c = r & 255;
    float v = (o < 256) ? qw[o * 256 + c] : (t ? kvtw[o * 256 + c] : kvrw[o * 256 + c]);
    Aqv[idx] = f2bf(v);
    return;
  }
  idx -= 2 * 512 * 256;
  if (idx < 2 * 16 * 2304) {
    int t = idx / 36864; int r = idx % 36864;
    int o = r / 2304; int rc = r % 2304; int tap = rc >> 8; int c = rc & 255;
    const float* w = t ? offtw : offrw;
    float v = (o < 8) ? w[(o * 256 + c) * 9 + tap] : 0.f;
    Aoff[idx] = f2bf(v);
    return;
  }
  idx -= 2 * 16 * 2304;
  if (idx < 256 * 512) {
    int seg = idx >> 11, o = (idx >> 3) & 255, e = idx & 7;
    Aout[idx] = f2bf(outw[o * 512 + seg * 8 + e]);
  }
}

// ---------------- K1: NCHW f32 -> NHWC bf16 transpose ----------------
__global__ void k_transpose(const float* rgb, const float* th, unsigned short* xT) {
  int bi = blockIdx.x;
  int ct = bi & 3;
  int nt = (bi >> 2) & 63;
  int b  = (bi >> 8) & 15;
  int t  = bi >> 12;
  const float* src = t ? th : rgb;
  int c0 = ct * 64, n0 = nt * 64;
  __shared__ float tile[64][65];
  int tid = threadIdx.x;
  int nl = tid & 63, cg = tid >> 6;
#pragma unroll
  for (int i = 0; i < 16; i++) {
    int c = cg * 16 + i;
    tile[c][nl] = src[(size_t)(b * 256 + c0 + c) * HWn + n0 + nl];
  }
  __syncthreads();
  int pr = tid >> 2, sg = tid & 3;
  unsigned short tmp[16];
#pragma unroll
  for (int j = 0; j < 16; j++) tmp[j] = f2bf(tile[sg * 16 + j][pr]);
  unsigned short* dst = xT + (size_t)t * Ntot * 256 +
                        (size_t)(b * HWn + n0 + pr) * 256 + c0 + sg * 16;
  *(uint4*)(dst)     = *(const uint4*)(tmp);
  *(uint4*)(dst + 8) = *(const uint4*)(tmp + 8);
}

// ---------------- K2: QV GEMM (BM=128,BN=128,BK=64; coalesced epilogue) ----
__global__ __launch_bounds__(512, 2) void k_qv(
    const unsigned short* Aqv, const unsigned short* xT,
    const float* qb, const float* kvrb, const float* kvtb,
    unsigned short* qs, unsigned short* vv) {
  __shared__ unsigned short smem[32768];   // 64 KB: K-loop dbuf; reused by epilogue
  int t  = blockIdx.z;
  int mt = blockIdx.y;
  int nt = blockIdx.x;
  int swznt = ((nt & 7) << 6) | (nt >> 3);   // XCD-chunked, bijective (512 % 8 == 0)
  int o0 = mt * 128;
  int n0 = swznt * 128;
  int tid = threadIdx.x;
  const unsigned short* Aq = Aqv + t * 512 * 256;
  const unsigned short* Xg = xT + (size_t)t * Ntot * 256 + (size_t)n0 * 256;

  auto stage = [&](int kb, int bb) {
    unsigned short* As = smem + bb * 8192;
    unsigned short* Xs = smem + 16384 + bb * 8192;
#pragma unroll
    for (int i = 0; i < 2; i++) {
      int cid = tid + i * 512;
      int row = cid >> 3, seg = cid & 7;
      int ss = seg ^ (row & 7);
      *(uint4*)(&As[row * 64 + seg * 8]) =
          *(const uint4*)(Aq + (size_t)(o0 + row) * 256 + kb * 64 + ss * 8);
    }
#pragma unroll
    for (int i = 0; i < 2; i++) {
      int cid = tid + i * 512;
      int row = cid >> 3, seg = cid & 7;
      int ss = seg ^ (row & 7);
      *(uint4*)(&Xs[row * 64 + seg * 8]) =
          *(const uint4*)(Xg + (size_t)row * 256 + kb * 64 + ss * 8);
    }
  };

  int w = __builtin_amdgcn_readfirstlane(tid >> 6);
  int lane = tid & 63;
  int wo = w & 1, wn = w >> 1;   // 2x64 o-rows, 4x32 pixels
  int r16 = lane & 15, q4 = lane >> 4;

  f32x4 acc[4][2];
#pragma unroll
  for (int a = 0; a < 4; a++) { acc[a][0] = f32x4{0.f,0.f,0.f,0.f}; acc[a][1] = f32x4{0.f,0.f,0.f,0.f}; }

  stage(0, 0);
  __syncthreads();
#pragma unroll
  for (int kb = 0; kb < 4; kb++) {
    if (kb < 3) stage(kb + 1, (kb + 1) & 1);
    const unsigned short* As = smem + (kb & 1) * 8192;
    const unsigned short* Xs = smem + 16384 + (kb & 1) * 8192;
#pragma unroll
    for (int ks = 0; ks < 2; ks++) {
      uint4 af[4], bfr[2];
#pragma unroll
      for (int oi = 0; oi < 4; oi++) {
        int row = wo * 64 + oi * 16 + r16;
        int seg = (ks * 4 + q4) ^ (row & 7);
        af[oi] = *(const uint4*)(&As[row * 64 + seg * 8]);
      }
#pragma unroll
      for (int ni = 0; ni < 2; ni++) {
        int row = wn * 32 + ni * 16 + r16;
        int seg = (ks * 4 + q4) ^ (row & 7);
        bfr[ni] = *(const uint4*)(&Xs[row * 64 + seg * 8]);
      }
#pragma unroll
      for (int oi = 0; oi < 4; oi++)
#pragma unroll
        for (int ni = 0; ni < 2; ni++)
          acc[oi][ni] = __builtin_amdgcn_mfma_f32_16x16x32_bf16(
              asbf(af[oi]), asbf(bfr[ni]), acc[oi][ni], 0, 0, 0);
    }
    __syncthreads();
  }

  // epilogue: bias (+sigmoid for q) -> LDS [128 n][132 o-pad] -> coalesced global
  bool isq = (mt < 2);
  const float* bias = isq ? qb : (t ? kvtb : kvrb);
  float4 bv[4];
#pragma unroll
  for (int oi = 0; oi < 4; oi++)
    bv[oi] = *(const float4*)(&bias[o0 + wo * 64 + oi * 16 + q4 * 4]);
#pragma unroll
  for (int oi = 0; oi < 4; oi++) {
    int ol = wo * 64 + oi * 16 + q4 * 4;
#pragma unroll
    for (int ni = 0; ni < 2; ni++) {
      int nl = wn * 32 + ni * 16 + r16;
      unsigned short pk[4];
#pragma unroll
      for (int j = 0; j < 4; j++) {
        float val = acc[oi][ni][j] + ((const float*)&bv[oi])[j];
        if (isq) val = 1.f / (1.f + __expf(-val));
        pk[j] = f2bf(val);
      }
      *(uint2*)(&smem[nl * 132 + ol]) = *(const uint2*)(pk);
    }
  }
  __syncthreads();
  unsigned short* outp = (isq ? qs : vv) + (size_t)t * Ntot * 256 + (mt & 1) * 128;
#pragma unroll
  for (int pass = 0; pass < 4; pass++) {
    int nl = pass * 32 + (tid >> 4);
    int c  = tid & 15;
    uint4 vq = *(const uint4*)(&smem[nl * 132 + c * 8]);
    *(uint4*)(outp + (size_t)(n0 + nl) * 256 + c * 8) = vq;
  }
}

// ---------------- K3: 3x3 offset conv. LDS weights, pipelined B loads ----------------
__global__ __launch_bounds__(256, 4) void k_off(
    const unsigned short* Aoff, const unsigned short* xT,
    const float* offrb, const float* offtb, float* offo) {
  __shared__ unsigned short Alds[9 * 8 * 264 + 264];  // 38544 B
  int t  = blockIdx.y;
  int bh = blockIdx.x;
  int swz = ((bh & 7) << 7) | (bh >> 3);   // XCD-chunked, bijective
  int b = swz >> 6, h = swz & 63;
  int tid = threadIdx.x;
  const unsigned short* Aw = Aoff + t * 36864;   // [row16][tap9][c256]

#pragma unroll
  for (int i = 0; i < 9; i++) {
    int cid = tid + i * 256;
    int o = cid / 288;
    int rem = cid - o * 288;
    int tap = rem >> 5, cg = rem & 31;
    uint4 v = *(const uint4*)(Aw + o * 2304 + tap * 256 + cg * 8);
    *(uint4*)(&Alds[(tap * 8 + o) * 264 + cg * 8]) = v;
  }
  if (tid < 33) {
    uint4 z; z.x = 0; z.y = 0; z.z = 0; z.w = 0;
    *(uint4*)(&Alds[19008 + tid * 8]) = z;
  }
  __syncthreads();

  int lane = tid & 63, w = tid >> 6;
  int r16 = lane & 15, q4 = lane >> 4;
  int wl = w * 16 + r16;
  const unsigned short* xin = xT + (size_t)(t ? 0 : 1) * Ntot * 256;
  int zbase = 19008 + q4 * 8;
  int abase = r16 * 264 + q4 * 8;
  bool rowok = (r16 < 8);

  f32x4 acc = {0.f, 0.f, 0.f, 0.f};
  uint4 bufA[8], bufB[8];

#define LOADT(buf, tap) {                                                      \
    int dy = (tap) / 3 - 1, dx = (tap) % 3 - 1;                                \
    int hh = h + dy, ww = wl + dx;                                             \
    bool ok = (hh >= 0 && hh < 64 && ww >= 0 && ww < 64);                      \
    int hc = hh < 0 ? 0 : (hh > 63 ? 63 : hh);                                 \
    int wc = ww < 0 ? 0 : (ww > 63 ? 63 : ww);                                 \
    const unsigned short* p =                                                  \
        xin + (size_t)(((b * 64 + hc) * 64 + wc) * 256) + q4 * 8;              \
    _Pragma("unroll") for (int ks = 0; ks < 8; ks++) {                         \
      uint4 v = *(const uint4*)(p + ks * 32);                                  \
      if (!ok) { v.x = 0; v.y = 0; v.z = 0; v.w = 0; }                         \
      buf[ks] = v;                                                             \
    } }

#define COMPT(buf, tap) {                                                      \
    _Pragma("unroll") for (int ks = 0; ks < 8; ks++) {                         \
      int aofs = rowok ? ((tap) * 8 * 264 + abase + ks * 32) : (zbase + ks * 32); \
      uint4 af = *(const uint4*)(&Alds[aofs]);                                 \
      acc = __builtin_amdgcn_mfma_f32_16x16x32_bf16(asbf(af), asbf(buf[ks]),   \
                                                    acc, 0, 0, 0);             \
    } }

  LOADT(bufA, 0)
  LOADT(bufB, 1)
  COMPT(bufA, 0)
  LOADT(bufA, 2)
  COMPT(bufB, 1)
  LOADT(bufB, 3)
  COMPT(bufA, 2)
  LOADT(bufA, 4)
  COMPT(bufB, 3)
  LOADT(bufB, 5)
  COMPT(bufA, 4)
  LOADT(bufA, 6)
  COMPT(bufB, 5)
  LOADT(bufB, 7)
  COMPT(bufA, 6)
  LOADT(bufA, 8)
  COMPT(bufB, 7)
  COMPT(bufA, 8)
#undef LOADT
#undef COMPT

  if (lane < 32) {
    const float* ob = t ? offtb : offrb;
    int n = (b * 64 + h) * 64 + wl;
    float4 r;
    r.x = acc[0] + ob[q4 * 4 + 0];
    r.y = acc[1] + ob[q4 * 4 + 1];
    r.z = acc[2] + ob[q4 * 4 + 2];
    r.w = acc[3] + ob[q4 * 4 + 3];
    *(float4*)(offo + (size_t)t * Ntot * 8 + (size_t)n * 8 + q4 * 4) = r;
  }
}

// ---------------- K4: fused deform-gather + attn + final GEMM + skip + BN partials --
// v5: 16 px/block, 4096 blocks, 32 thr/px with 8 ch each (acc[8], 4 loads in
// flight) -> natural VGPR ~55-60 <= 64 quantum -> 4 waves/SIMD occupancy tier.
__global__ __launch_bounds__(512, 4) void k_fuse(
    const unsigned short* qs, const unsigned short* vv, const float* offo,
    const unsigned short* Apk, const float* outb,
    const float* rgb, const float* th, float* dout, float* partial) {
  __shared__ unsigned short cc[16 * 512];    // [pxL][512ch] XOR-swizzled, 16KB
  __shared__ float bstat[256][2];
  int tid = threadIdx.x;
  int bi  = blockIdx.x;                       // 4096
  int swz = ((bi & 7) << 9) | (bi >> 3);      // XCD-chunked, bijective (4096%8==0)
  int b = swz >> 8;
  int h = (swz >> 2) & 63;
  int px0 = (swz & 3) * 16;
  if (tid < 256) { bstat[tid][0] = 0.f; bstat[tid][1] = 0.f; }

  // ---- phase 1: gather (8 channels per thread per pass) ----
  {
    int pxL = tid >> 5, chunk = tid & 31;
    int px = px0 + pxL;
    int n = (b * 64 + h) * 64 + px;
    int c0 = chunk * 8;
    int sw = pxL & 7;
#pragma unroll
    for (int pass = 0; pass < 2; pass++) {
      // pass0 -> ch 0..255  = sig(q_rgb) * deform(v_th, off_th2rgb)
      // pass1 -> ch 256..511 = sig(q_th) * deform(v_rgb, off_rgb2th)
      const unsigned short* vsrc = vv + (size_t)(pass ? 0 : 1) * Ntot * 256;
      const float* offp = offo + (size_t)(pass ? 0 : 1) * Ntot * 8 + (size_t)n * 8;
      const unsigned short* qsrc = qs + (size_t)(pass ? 1 : 0) * Ntot * 256 + (size_t)n * 256;
      uint4 q0 = *(const uint4*)(qsrc + c0);
      float acc[8];
#pragma unroll
      for (int i = 0; i < 8; i++) acc[i] = 0.f;
#pragma unroll
      for (int p = 0; p < 4; p++) {
        float dx = offp[2 * p], dy = offp[2 * p + 1];
        float xf = (float)px + dx * (63.f / 64.f);
        float yf = (float)h  + dy * (63.f / 64.f);
        float x0f = floorf(xf), y0f = floorf(yf);
        float wx = xf - x0f, wy = yf - y0f;
        int x0 = (int)x0f, y0 = (int)y0f;
        float cwgt[4];
        int   coff[4];
#pragma unroll
        for (int c = 0; c < 4; c++) {
          int cy2 = c >> 1, cx2 = c & 1;
          int ix = x0 + cx2, iy = y0 + cy2;
          bool ok = (ix >= 0 && ix < 64 && iy >= 0 && iy < 64);
          int ixc = ix < 0 ? 0 : (ix > 63 ? 63 : ix);
          int iyc = iy < 0 ? 0 : (iy > 63 ? 63 : iy);
          float wgt = (cx2 ? wx : 1.f - wx) * (cy2 ? wy : 1.f - wy);
          cwgt[c] = ok ? wgt : 0.f;
          coff[c] = ((b * 64 + iyc) * 64 + ixc) * 256 + c0;
        }
        // batch 4 loads, then FMA
        uint4 ra = *(const uint4*)(vsrc + coff[0]);
        uint4 rb = *(const uint4*)(vsrc + coff[1]);
        uint4 rc = *(const uint4*)(vsrc + coff[2]);
        uint4 rd = *(const uint4*)(vsrc + coff[3]);
#define FMA4(r, wv2) { const unsigned short* a0 = (const unsigned short*)&(r); \
        _Pragma("unroll") for (int e = 0; e < 8; e++) acc[e] += (wv2) * bf2f(a0[e]); }
        FMA4(ra, cwgt[0])
        FMA4(rb, cwgt[1])
        FMA4(rc, cwgt[2])
        FMA4(rd, cwgt[3])
#undef FMA4
      }
      const unsigned short* qp0 = (const unsigned short*)&q0;
      unsigned short pk[8];
#pragma unroll
      for (int e = 0; e < 8; e++) pk[e] = f2bf(0.25f * acc[e] * bf2f(qp0[e]));
      *(uint4*)(&cc[pxL * 512 + ((pass * 32 + chunk) ^ sw) * 8]) = *(const uint4*)(pk);
    }
  }
  __syncthreads();

  // ---- phase 2: GEMM 256 o x 16 px, 8 waves x (32 o) ----
  int lane = tid & 63, wv = tid >> 6;
  int r16 = lane & 15, q4 = lane >> 4;
  f32x4 acc2[2];
  acc2[0] = f32x4{0.f, 0.f, 0.f, 0.f};
  acc2[1] = f32x4{0.f, 0.f, 0.f, 0.f};
#pragma unroll
  for (int kst = 0; kst < 16; kst++) {
    int slot = (kst * 4 + q4) ^ (r16 & 7);
    uint4 bfr = *(const uint4*)(&cc[r16 * 512 + slot * 8]);
#pragma unroll
    for (int oi = 0; oi < 2; oi++) {
      int o = wv * 32 + oi * 16 + r16;
      uint4 a = *(const uint4*)(Apk + (size_t)((kst * 4 + q4) * 256 + o) * 8);
      acc2[oi] = __builtin_amdgcn_mfma_f32_16x16x32_bf16(asbf(a), asbf(bfr), acc2[oi], 0, 0, 0);
    }
  }
  // epilogue: bias + skip + store + BN partials
#pragma unroll
  for (int oi = 0; oi < 2; oi++) {
    int ob = wv * 32 + oi * 16 + q4 * 4;
#pragma unroll
    for (int j = 0; j < 4; j++) {
      int o = ob + j;
      int hw = h * 64 + px0 + r16;
      size_t gidx = (size_t)(b * 256 + o) * HWn + hw;
      float val = acc2[oi][j] + outb[o] + 0.5f * (rgb[gidx] + th[gidx]);
      dout[gidx] = val;
      float s1 = val, s2 = val * val;
#pragma unroll
      for (int m = 1; m < 16; m <<= 1) {
        s1 += __shfl_xor(s1, m, 16);
        s2 += __shfl_xor(s2, m, 16);
      }
      if (r16 == 0) { atomicAdd(&bstat[o][0], s1); atomicAdd(&bstat[o][1], s2); }
    }
  }
  __syncthreads();
  if (tid < 256) {
    partial[(size_t)bi * 512 + tid]       = bstat[tid][0];
    partial[(size_t)bi * 512 + 256 + tid] = bstat[tid][1];
  }
}

// ---------------- K5: reduce partials -> scale/shift ----------------
__global__ void k_stats(const float* partial, const float* gamma, const float* beta,
                        float* sstats) {
  int c = blockIdx.x, tid = threadIdx.x;
  float s1 = 0.f, s2 = 0.f;
  for (int i = tid; i < 4096; i += 256) {
    s1 += partial[(size_t)i * 512 + c];
    s2 += partial[(size_t)i * 512 + 256 + c];
  }
  __shared__ float r1[256], r2[256];
  r1[tid] = s1; r2[tid] = s2;
  __syncthreads();
  for (int st = 128; st > 0; st >>= 1) {
    if (tid < st) { r1[tid] += r1[tid + st]; r2[tid] += r2[tid + st]; }
    __syncthreads();
  }
  if (tid == 0) {
    float mean = r1[0] / 65536.f;
    float var  = r2[0] / 65536.f - mean * mean;
    float scale = gamma[c] / sqrtf(var + 1e-5f);
    sstats[c]       = scale;
    sstats[256 + c] = beta[c] - mean * scale;
  }
}

// ---------------- K6: BN apply in-place on d_out ----------------
__global__ void k_bn(float* dout, const float* sstats) {
  int idx = blockIdx.x * 256 + threadIdx.x;
  size_t base = (size_t)idx * 4;
  int c = (int)((base >> 12) & 255);
  float4 v = *(float4*)(dout + base);
  float sc = sstats[c], sh = sstats[256 + c];
  v.x = v.x * sc + sh; v.y = v.y * sc + sh;
  v.z = v.z * sc + sh; v.w = v.w * sc + sh;
  *(float4*)(dout + base) = v;
}

extern "C" void kernel_launch(void* const* d_in, const int* in_sizes, int n_in,
                              void* d_out, int out_size, void* d_ws, size_t ws_size,
                              hipStream_t stream) {
  const float* rgb   = (const float*)d_in[0];
  const float* th    = (const float*)d_in[1];
  const float* qw    = (const float*)d_in[2];
  const float* qb    = (const float*)d_in[3];
  const float* kvrw  = (const float*)d_in[4];
  const float* kvrb  = (const float*)d_in[5];
  const float* kvtw  = (const float*)d_in[6];
  const float* kvtb  = (const float*)d_in[7];
  const float* offrw = (const float*)d_in[8];
  const float* offrb = (const float*)d_in[9];
  const float* offtw = (const float*)d_in[10];
  const float* offtb = (const float*)d_in[11];
  const float* outw  = (const float*)d_in[12];
  const float* outb  = (const float*)d_in[13];
  const float* gamma = (const float*)d_in[14];
  const float* beta  = (const float*)d_in[15];
  float* dout = (float*)d_out;

  unsigned short* xT   = (unsigned short*)d_ws;       // 64 MB
  unsigned short* qsb  = xT  + (size_t)2 * Ntot * 256;
  unsigned short* vvb  = qsb + (size_t)2 * Ntot * 256;
  float* offo          = (float*)(vvb + (size_t)2 * Ntot * 256);
  unsigned short* Aqv  = (unsigned short*)(offo + (size_t)2 * Ntot * 8);
  unsigned short* Aoff = Aqv + 2 * 512 * 256;
  unsigned short* Aout = Aoff + 2 * 16 * 2304;        // packed Apk
  float* partial       = (float*)(Aout + 256 * 512);  // 4096 * 512 f32
  float* sstats        = partial + (size_t)4096 * 512;

  k_prep<<<1824, 256, 0, stream>>>(qw, kvrw, kvtw, offrw, offtw, outw, Aqv, Aoff, Aout);
  k_transpose<<<8192, 256, 0, stream>>>(rgb, th, xT);
  k_qv<<<dim3(512, 4, 2), 512, 0, stream>>>(Aqv, xT, qb, kvrb, kvtb, qsb, vvb);
  k_off<<<dim3(1024, 2), 256, 0, stream>>>(Aoff, xT, offrb, offtb, offo);
  k_fuse<<<4096, 512, 0, stream>>>(qsb, vvb, offo, Aout, outb, rgb, th, dout, partial);
  k_stats<<<256, 256, 0, stream>>>(partial, gamma, beta, sstats);
  k_bn<<<16384, 256, 0, stream>>>(dout, sstats);
}